// Round 3
// baseline (225.073 us; speedup 1.0000x reference)
//
#include <hip/hip_runtime.h>
#include <hip/hip_fp16.h>

#define D_NODE 64
#define H_DIM  128

struct Half8 { __half2 h[4]; };

// ---------------------------------------------------------------------------
// Fused prep kernel. Block roles by blockIdx.x range:
//   [0, f2hS)            : f32->f16 convert emb_s   (256 thr, Half8 each)
//   [f2hS, f2hS+f2hA)    : f32->f16 convert emb_a
//   [.., +pS)            : P rows for s-table (32 rows/block, col-register GEMM)
//   [.., +pA)            : P rows for a-table
//   [.., +zB)            : zero segsum
// ---------------------------------------------------------------------------
__global__ void __launch_bounds__(256)
prep_kernel(const float* __restrict__ emb_s,
            const float* __restrict__ emb_a,
            const float* __restrict__ W1,
            const float* __restrict__ b1,
            __half* __restrict__ e16s,
            __half* __restrict__ e16a,
            __half* __restrict__ P,
            float* __restrict__ segsum,
            int numS, int numA,
            int f2hS, int f2hA, int pS, int pA, int zB)
{
    int b = blockIdx.x;
    const int t = threadIdx.x;

    // ---- role: f16 conversion ----
    if (b < f2hS + f2hA) {
        const bool isS = (b < f2hS);
        const float* src = isS ? emb_s : emb_a;
        __half* dst = isS ? e16s : e16a;
        const int n8 = (isS ? numS : numA) * D_NODE / 8;
        const int i = (isS ? b : b - f2hS) * 256 + t;
        if (i < n8) {
            const float4* s4 = (const float4*)src;
            float4 a = s4[2 * i];
            float4 c = s4[2 * i + 1];
            Half8 o;
            o.h[0] = __floats2half2_rn(a.x, a.y);
            o.h[1] = __floats2half2_rn(a.z, a.w);
            o.h[2] = __floats2half2_rn(c.x, c.y);
            o.h[3] = __floats2half2_rn(c.z, c.w);
            ((Half8*)dst)[i] = o;
        }
        return;
    }
    b -= f2hS + f2hA;

    // ---- role: P precompute ----
    if (b < pS + pA) {
        const bool isS = (b < pS);
        const int pb = isS ? b : b - pS;
        const float* Wh = isS ? W1 : (W1 + D_NODE * H_DIM);
        const int col = t & 127;

        float w[D_NODE];
#pragma unroll
        for (int k = 0; k < D_NODE; ++k) w[k] = Wh[k * H_DIM + col];

        const float bias = isS ? b1[col] : 0.0f;
        const float* etab = isS ? emb_s : emb_a;
        const int rowsTot = isS ? numS : numA;
        const int pOff = isS ? 0 : numS;
        const int rowBase = pb * 32 + (t >> 7) * 16;

        for (int r = 0; r < 16; ++r) {
            const int row = rowBase + r;
            if (row >= rowsTot) break;
            const float* erow = etab + (size_t)row * D_NODE;
            float acc = bias;
#pragma unroll
            for (int k = 0; k < D_NODE; ++k)
                acc = fmaf(erow[k], w[k], acc);
            P[(size_t)(pOff + row) * H_DIM + col] = __float2half(acc);
        }
        return;
    }
    b -= pS + pA;

    // ---- role: zero segsum ----
    {
        const int i = b * 256 + t;
        if (i < numS) segsum[i] = 0.0f;
    }
}

// ---------------------------------------------------------------------------
// Main edge pass: 8 lanes per edge.
//   cost = ||es-ea|| * sigmoid( dot(relu(P_s+P_a), W2) + b2 )
//   atomicAdd(segsum[s], exp(-cost/temp))   (no seg-max: vals in [-20,0])
// ---------------------------------------------------------------------------
__global__ void __launch_bounds__(256)
edge_main_kernel(const __half* __restrict__ e16s,
                 const __half* __restrict__ e16a,
                 const int* __restrict__ idx,
                 const __half* __restrict__ P,
                 const float* __restrict__ W2,
                 const float* __restrict__ b2,
                 const float* __restrict__ logT,
                 float* __restrict__ out_costs,
                 float* __restrict__ segsum,
                 int E, int numS)
{
    const int gid = blockIdx.x * 256 + (int)threadIdx.x;
    const int e = gid >> 3;
    const int t = gid & 7;
    if (e >= E) return;

    const int s = idx[e];
    const int a = idx[E + e];

    // --- norm partial: 8 halves of es/ea per lane ---
    const uint4* es8 = (const uint4*)(e16s + (size_t)s * D_NODE);
    const uint4* ea8 = (const uint4*)(e16a + (size_t)a * D_NODE);
    uint4 xs = es8[t];
    uint4 xa = ea8[t];
    const __half2* hs = (const __half2*)&xs;
    const __half2* ha = (const __half2*)&xa;
    float nacc = 0.0f;
#pragma unroll
    for (int k = 0; k < 4; ++k) {
        float2 fs = __half22float2(hs[k]);
        float2 fa = __half22float2(ha[k]);
        float d0 = fs.x - fa.x, d1 = fs.y - fa.y;
        nacc = fmaf(d0, d0, nacc);
        nacc = fmaf(d1, d1, nacc);
    }

    // --- gate partial: h-chunks t and t+8 (8 halves each) ---
    const uint4* ps8 = (const uint4*)(P + (size_t)s * H_DIM);
    const uint4* pa8 = (const uint4*)(P + (size_t)(numS + a) * H_DIM);
    const float4* w4 = (const float4*)W2;
    float g = 0.0f;
#pragma unroll
    for (int c = 0; c < 2; ++c) {
        const int chunk = t + c * 8;
        uint4 up = ps8[chunk];
        uint4 uq = pa8[chunk];
        const __half2* hp = (const __half2*)&up;
        const __half2* hq = (const __half2*)&uq;
        float4 w0 = w4[chunk * 2];
        float4 w1 = w4[chunk * 2 + 1];
        float wv[8] = {w0.x, w0.y, w0.z, w0.w, w1.x, w1.y, w1.z, w1.w};
#pragma unroll
        for (int k = 0; k < 4; ++k) {
            float2 fp = __half22float2(hp[k]);
            float2 fq = __half22float2(hq[k]);
            float h0 = fmaxf(fp.x + fq.x, 0.0f);
            float h1 = fmaxf(fp.y + fq.y, 0.0f);
            g = fmaf(h0, wv[2 * k], g);
            g = fmaf(h1, wv[2 * k + 1], g);
        }
    }

    // --- 8-lane reduction ---
#pragma unroll
    for (int m = 1; m < 8; m <<= 1) {
        nacc += __shfl_xor(nacc, m);
        g    += __shfl_xor(g, m);
    }

    if (t == 0) {
        const float z = g + b2[0];
        const float gate = 1.0f / (1.0f + __expf(-z));
        const float cost = sqrtf(nacc) * gate;
        out_costs[e] = cost;
        const float temp = __expf(logT[0]);
        atomicAdd(&segsum[s], __expf(-cost / temp));
    }
}

// ---------------------------------------------------------------------------
// edge_weights = exp(-cost/temp) / segsum[s]  (recompute ex from cost)
// ---------------------------------------------------------------------------
__global__ void __launch_bounds__(256)
edge_norm_kernel(const int* __restrict__ idx,
                 const float* __restrict__ out_costs,
                 const float* __restrict__ segsum,
                 const float* __restrict__ logT,
                 float* __restrict__ out_w,
                 int E)
{
    const int e = blockIdx.x * blockDim.x + threadIdx.x;
    if (e >= E) return;
    const int s = idx[e];
    const float temp = __expf(logT[0]);
    const float ex = __expf(-out_costs[e] / temp);
    out_w[e] = ex / segsum[s];
}

// ---------------------------------------------------------------------------
extern "C" void kernel_launch(void* const* d_in, const int* in_sizes, int n_in,
                              void* d_out, int out_size, void* d_ws, size_t ws_size,
                              hipStream_t stream)
{
    const float* emb_s = (const float*)d_in[0];
    const float* emb_a = (const float*)d_in[1];
    const int*   idx   = (const int*)d_in[2];
    const float* W1    = (const float*)d_in[3];
    const float* b1    = (const float*)d_in[4];
    const float* W2    = (const float*)d_in[5];
    const float* b2    = (const float*)d_in[6];
    const float* logT  = (const float*)d_in[7];

    const int numS = in_sizes[0] / D_NODE;
    const int numA = in_sizes[1] / D_NODE;
    const int E    = in_sizes[2] / 2;

    float* out = (float*)d_out;            // [0,E) weights, [E,2E) costs

    // workspace layout
    char* ws = (char*)d_ws;
    __half* P      = (__half*)ws;   ws += (size_t)(numS + numA) * H_DIM * sizeof(__half);
    __half* e16s   = (__half*)ws;   ws += (size_t)numS * D_NODE * sizeof(__half);
    __half* e16a   = (__half*)ws;   ws += (size_t)numA * D_NODE * sizeof(__half);
    float*  segsum = (float*)ws;

    // fused prep: conversions + P + segsum zeroing, one launch
    const int f2hS = (numS * D_NODE / 8 + 255) / 256;
    const int f2hA = (numA * D_NODE / 8 + 255) / 256;
    const int pS   = (numS + 31) / 32;
    const int pA   = (numA + 31) / 32;
    const int zB   = (numS + 255) / 256;
    prep_kernel<<<f2hS + f2hA + pS + pA + zB, 256, 0, stream>>>(
        emb_s, emb_a, W1, b1, e16s, e16a, P, segsum,
        numS, numA, f2hS, f2hA, pS, pA, zB);

    // main edge pass (8 lanes/edge)
    {
        const long long threads = (long long)E * 8;
        const int blocks = (int)((threads + 255) / 256);
        edge_main_kernel<<<blocks, 256, 0, stream>>>(e16s, e16a, idx, P, W2, b2,
                                                     logT, out + E, segsum,
                                                     E, numS);
    }

    edge_norm_kernel<<<(E + 255) / 256, 256, 0, stream>>>(idx, out + E, segsum,
                                                          logT, out, E);
}

// Round 4
// 207.600 us; speedup vs baseline: 1.0842x; 1.0842x over previous
//
#include <hip/hip_runtime.h>
#include <hip/hip_fp16.h>

#define D_NODE 64
#define H_DIM  128
#define REC_H  192   // halves per node record: 64 (e16) + 128 (P)

struct Half8 { __half2 h[4]; };

// ---------------------------------------------------------------------------
// Streaming prep (low VGPR): f32->f16 conversion of both embedding tables
// into interleaved records, plus segsum zeroing.
//   record[node] = [ e16 row : 64 halves | P row : 128 halves ]  (384 B)
// ---------------------------------------------------------------------------
__global__ void __launch_bounds__(256)
convert_zero_kernel(const float* __restrict__ emb_s,
                    const float* __restrict__ emb_a,
                    __half* __restrict__ recS,
                    __half* __restrict__ recA,
                    float* __restrict__ segsum,
                    int numS, int numA)
{
    const int gid = blockIdx.x * 256 + (int)threadIdx.x;
    const int n8s = numS * (D_NODE / 8);
    const int n8a = numA * (D_NODE / 8);

    if (gid < n8s + n8a) {
        const bool isS = (gid < n8s);
        const int i = isS ? gid : gid - n8s;
        const float4* src = (const float4*)(isS ? emb_s : emb_a);
        __half* rec = isS ? recS : recA;
        float4 a = src[2 * i];
        float4 c = src[2 * i + 1];
        Half8 o;
        o.h[0] = __floats2half2_rn(a.x, a.y);
        o.h[1] = __floats2half2_rn(a.z, a.w);
        o.h[2] = __floats2half2_rn(c.x, c.y);
        o.h[3] = __floats2half2_rn(c.z, c.w);
        const int row = i >> 3;
        const int chunk = i & 7;
        ((Half8*)(rec + (size_t)row * REC_H))[chunk] = o;
    } else {
        const int i = gid - n8s - n8a;
        if (i < numS) segsum[i] = 0.0f;
    }
}

// ---------------------------------------------------------------------------
// P precompute into the record's P region (fp16).
//   recS[row].P = emb_s[row] @ W1[0:64,:] + b1
//   recA[row].P = emb_a[row] @ W1[64:128,:]
// 128 threads/block (thread j = column j), 64 rows/block, W half in regs.
// Compute-bound standalone kernel; high VGPR is acceptable here.
// ---------------------------------------------------------------------------
__global__ void __launch_bounds__(128)
precompute_P_kernel(const float* __restrict__ emb_s,
                    const float* __restrict__ emb_a,
                    const float* __restrict__ W1,
                    const float* __restrict__ b1,
                    __half* __restrict__ recS,
                    __half* __restrict__ recA,
                    int numS, int numA)
{
    const int col = threadIdx.x;
    const int sBlocks = (numS + 63) / 64;
    const bool isS = ((int)blockIdx.x < sBlocks);

    const float* Wh = isS ? W1 : (W1 + D_NODE * H_DIM);
    float w[D_NODE];
#pragma unroll
    for (int k = 0; k < D_NODE; ++k) w[k] = Wh[k * H_DIM + col];

    const float bias = isS ? b1[col] : 0.0f;
    const int rowBase = (isS ? (int)blockIdx.x : ((int)blockIdx.x - sBlocks)) * 64;
    const float* etab = isS ? emb_s : emb_a;
    __half* rec = isS ? recS : recA;
    const int rowsTot = isS ? numS : numA;

    for (int r = 0; r < 64; ++r) {
        const int row = rowBase + r;
        if (row >= rowsTot) break;
        const float* erow = etab + (size_t)row * D_NODE;
        float acc = bias;
#pragma unroll
        for (int k = 0; k < D_NODE; ++k)
            acc = fmaf(erow[k], w[k], acc);
        rec[(size_t)row * REC_H + D_NODE + col] = __float2half(acc);
    }
}

// ---------------------------------------------------------------------------
// Main edge pass: 8 lanes per edge, gathers 2 contiguous 384 B records.
//   cost = ||es-ea|| * sigmoid( dot(relu(P_s+P_a), W2) + b2 )
//   atomicAdd(segsum[s], exp(-cost/temp))   (no seg-max: vals in [-20,0])
// ---------------------------------------------------------------------------
__global__ void __launch_bounds__(256)
edge_main_kernel(const __half* __restrict__ recS,
                 const __half* __restrict__ recA,
                 const int* __restrict__ idx,
                 const float* __restrict__ W2,
                 const float* __restrict__ b2,
                 const float* __restrict__ logT,
                 float* __restrict__ out_costs,
                 float* __restrict__ segsum,
                 int E)
{
    const int gid = blockIdx.x * 256 + (int)threadIdx.x;
    const int e = gid >> 3;
    const int t = gid & 7;
    if (e >= E) return;

    const int s = idx[e];
    const int a = idx[E + e];

    const uint4* rs = (const uint4*)(recS + (size_t)s * REC_H);
    const uint4* ra = (const uint4*)(recA + (size_t)a * REC_H);

    // --- norm partial: e16 chunk t (8 halves) ---
    uint4 xs = rs[t];
    uint4 xa = ra[t];
    const __half2* hs = (const __half2*)&xs;
    const __half2* ha = (const __half2*)&xa;
    float nacc = 0.0f;
#pragma unroll
    for (int k = 0; k < 4; ++k) {
        float2 fs = __half22float2(hs[k]);
        float2 fa = __half22float2(ha[k]);
        float d0 = fs.x - fa.x, d1 = fs.y - fa.y;
        nacc = fmaf(d0, d0, nacc);
        nacc = fmaf(d1, d1, nacc);
    }

    // --- gate partials: P chunks t and t+8 (uint4 idx 8+t, 16+t) ---
    const float4* w4 = (const float4*)W2;
    float g = 0.0f;
#pragma unroll
    for (int c = 0; c < 2; ++c) {
        const int chunk = t + c * 8;
        uint4 up = rs[8 + chunk];
        uint4 uq = ra[8 + chunk];
        const __half2* hp = (const __half2*)&up;
        const __half2* hq = (const __half2*)&uq;
        float4 w0 = w4[chunk * 2];
        float4 w1 = w4[chunk * 2 + 1];
        float wv[8] = {w0.x, w0.y, w0.z, w0.w, w1.x, w1.y, w1.z, w1.w};
#pragma unroll
        for (int k = 0; k < 4; ++k) {
            float2 fp = __half22float2(hp[k]);
            float2 fq = __half22float2(hq[k]);
            float h0 = fmaxf(fp.x + fq.x, 0.0f);
            float h1 = fmaxf(fp.y + fq.y, 0.0f);
            g = fmaf(h0, wv[2 * k], g);
            g = fmaf(h1, wv[2 * k + 1], g);
        }
    }

    // --- 8-lane reduction ---
#pragma unroll
    for (int m = 1; m < 8; m <<= 1) {
        nacc += __shfl_xor(nacc, m);
        g    += __shfl_xor(g, m);
    }

    if (t == 0) {
        const float z = g + b2[0];
        const float gate = 1.0f / (1.0f + __expf(-z));
        const float cost = sqrtf(nacc) * gate;
        out_costs[e] = cost;
        const float temp = __expf(logT[0]);
        atomicAdd(&segsum[s], __expf(-cost / temp));
    }
}

// ---------------------------------------------------------------------------
// edge_weights = exp(-cost/temp) / segsum[s]  (recompute ex from cost)
// ---------------------------------------------------------------------------
__global__ void __launch_bounds__(256)
edge_norm_kernel(const int* __restrict__ idx,
                 const float* __restrict__ out_costs,
                 const float* __restrict__ segsum,
                 const float* __restrict__ logT,
                 float* __restrict__ out_w,
                 int E)
{
    const int e = blockIdx.x * blockDim.x + threadIdx.x;
    if (e >= E) return;
    const int s = idx[e];
    const float temp = __expf(logT[0]);
    const float ex = __expf(-out_costs[e] / temp);
    out_w[e] = ex / segsum[s];
}

// ---------------------------------------------------------------------------
extern "C" void kernel_launch(void* const* d_in, const int* in_sizes, int n_in,
                              void* d_out, int out_size, void* d_ws, size_t ws_size,
                              hipStream_t stream)
{
    const float* emb_s = (const float*)d_in[0];
    const float* emb_a = (const float*)d_in[1];
    const int*   idx   = (const int*)d_in[2];
    const float* W1    = (const float*)d_in[3];
    const float* b1    = (const float*)d_in[4];
    const float* W2    = (const float*)d_in[5];
    const float* b2    = (const float*)d_in[6];
    const float* logT  = (const float*)d_in[7];

    const int numS = in_sizes[0] / D_NODE;
    const int numA = in_sizes[1] / D_NODE;
    const int E    = in_sizes[2] / 2;

    float* out = (float*)d_out;            // [0,E) weights, [E,2E) costs

    // workspace layout (records are 384 B, 16 B aligned)
    char* ws = (char*)d_ws;
    __half* recS   = (__half*)ws;   ws += (size_t)numS * REC_H * sizeof(__half);
    __half* recA   = (__half*)ws;   ws += (size_t)numA * REC_H * sizeof(__half);
    float*  segsum = (float*)ws;

    // streaming prep: conversions into records + segsum zeroing (low VGPR)
    {
        const int total = numS * (D_NODE / 8) + numA * (D_NODE / 8) + numS;
        convert_zero_kernel<<<(total + 255) / 256, 256, 0, stream>>>(
            emb_s, emb_a, recS, recA, segsum, numS, numA);
    }

    // P precompute (compute-bound, register-W)
    {
        const int pBlocks = (numS + 63) / 64 + (numA + 63) / 64;
        precompute_P_kernel<<<pBlocks, 128, 0, stream>>>(emb_s, emb_a, W1, b1,
                                                         recS, recA, numS, numA);
    }

    // main edge pass (8 lanes/edge)
    {
        const long long threads = (long long)E * 8;
        const int blocks = (int)((threads + 255) / 256);
        edge_main_kernel<<<blocks, 256, 0, stream>>>(recS, recA, idx, W2, b2,
                                                     logT, out + E, segsum, E);
    }

    edge_norm_kernel<<<(E + 255) / 256, 256, 0, stream>>>(idx, out + E, segsum,
                                                          logT, out, E);
}

// Round 5
// 201.454 us; speedup vs baseline: 1.1172x; 1.0305x over previous
//
#include <hip/hip_runtime.h>
#include <hip/hip_fp16.h>

#define D_NODE 64
#define H_DIM  128
#define REC_H  192   // halves per node record: 64 (e16) + 128 (P)

struct Half8 { __half2 h[4]; };

// ---------------------------------------------------------------------------
// Streaming prep (low VGPR): f32->f16 conversion of both embedding tables
// into interleaved records, plus segsum zeroing.
//   record[node] = [ e16 row : 64 halves | P row : 128 halves ]  (384 B)
// ---------------------------------------------------------------------------
__global__ void __launch_bounds__(256)
convert_zero_kernel(const float* __restrict__ emb_s,
                    const float* __restrict__ emb_a,
                    __half* __restrict__ recS,
                    __half* __restrict__ recA,
                    float* __restrict__ segsum,
                    int numS, int numA)
{
    const int gid = blockIdx.x * 256 + (int)threadIdx.x;
    const int n8s = numS * (D_NODE / 8);
    const int n8a = numA * (D_NODE / 8);

    if (gid < n8s + n8a) {
        const bool isS = (gid < n8s);
        const int i = isS ? gid : gid - n8s;
        const float4* src = (const float4*)(isS ? emb_s : emb_a);
        __half* rec = isS ? recS : recA;
        float4 a = src[2 * i];
        float4 c = src[2 * i + 1];
        Half8 o;
        o.h[0] = __floats2half2_rn(a.x, a.y);
        o.h[1] = __floats2half2_rn(a.z, a.w);
        o.h[2] = __floats2half2_rn(c.x, c.y);
        o.h[3] = __floats2half2_rn(c.z, c.w);
        const int row = i >> 3;
        const int chunk = i & 7;
        ((Half8*)(rec + (size_t)row * REC_H))[chunk] = o;
    } else {
        const int i = gid - n8s - n8a;
        if (i < numS) segsum[i] = 0.0f;
    }
}

// ---------------------------------------------------------------------------
// P precompute into the record's P region (fp16).
//   recS[row].P = emb_s[row] @ W1[0:64,:] + b1
//   recA[row].P = emb_a[row] @ W1[64:128,:]
// 256 threads/block, 64 rows/block. Embedding rows staged in LDS via
// coalesced float4 loads; W column in 64 registers; 4 independent
// accumulator chains (ILP-4) over fully-unrolled k.
// ---------------------------------------------------------------------------
__global__ void __launch_bounds__(256)
precompute_P_kernel(const float* __restrict__ emb_s,
                    const float* __restrict__ emb_a,
                    const float* __restrict__ W1,
                    const float* __restrict__ b1,
                    __half* __restrict__ recS,
                    __half* __restrict__ recA,
                    int numS, int numA)
{
    __shared__ float eTile[64 * D_NODE];   // 16 KB

    const int tid = threadIdx.x;
    const int sBlocks = (numS + 63) / 64;
    const bool isS = ((int)blockIdx.x < sBlocks);
    const int pb = isS ? (int)blockIdx.x : ((int)blockIdx.x - sBlocks);
    const float* etab = isS ? emb_s : emb_a;
    __half* rec = isS ? recS : recA;
    const int rowsTot = isS ? numS : numA;
    const int rowBase = pb * 64;

    // ---- stage 64 rows (16 KB) into LDS, coalesced float4 ----
    {
        const float4* src4 = (const float4*)etab;
        float4* dst4 = (float4*)eTile;
        const int maxIdx4 = rowsTot * (D_NODE / 4) - 1;
#pragma unroll
        for (int it = 0; it < 4; ++it) {
            const int i = tid + it * 256;
            int srcIdx = rowBase * (D_NODE / 4) + i;
            if (srcIdx > maxIdx4) srcIdx = maxIdx4;   // clamp (tail block)
            dst4[i] = src4[srcIdx];
        }
    }

    // ---- W column in registers ----
    const int col = tid & 127;
    const int rhalf = tid >> 7;            // 0 or 1: which 32-row half
    const float* Wh = isS ? W1 : (W1 + D_NODE * H_DIM);
    float w[D_NODE];
#pragma unroll
    for (int k = 0; k < D_NODE; ++k) w[k] = Wh[k * H_DIM + col];
    const float bias = isS ? b1[col] : 0.0f;

    __syncthreads();

    // ---- ILP-4 accumulation over 32 rows ----
    for (int r0 = rhalf * 32; r0 < rhalf * 32 + 32; r0 += 4) {
        const float4* e0 = (const float4*)&eTile[(r0 + 0) * D_NODE];
        const float4* e1 = (const float4*)&eTile[(r0 + 1) * D_NODE];
        const float4* e2 = (const float4*)&eTile[(r0 + 2) * D_NODE];
        const float4* e3 = (const float4*)&eTile[(r0 + 3) * D_NODE];
        float a0 = bias, a1 = bias, a2 = bias, a3 = bias;
#pragma unroll
        for (int k4 = 0; k4 < D_NODE / 4; ++k4) {
            const float4 v0 = e0[k4];
            const float4 v1 = e1[k4];
            const float4 v2 = e2[k4];
            const float4 v3 = e3[k4];
            const float w0 = w[4 * k4 + 0];
            const float w1 = w[4 * k4 + 1];
            const float w2 = w[4 * k4 + 2];
            const float w3 = w[4 * k4 + 3];
            a0 = fmaf(v0.x, w0, a0); a0 = fmaf(v0.y, w1, a0);
            a0 = fmaf(v0.z, w2, a0); a0 = fmaf(v0.w, w3, a0);
            a1 = fmaf(v1.x, w0, a1); a1 = fmaf(v1.y, w1, a1);
            a1 = fmaf(v1.z, w2, a1); a1 = fmaf(v1.w, w3, a1);
            a2 = fmaf(v2.x, w0, a2); a2 = fmaf(v2.y, w1, a2);
            a2 = fmaf(v2.z, w2, a2); a2 = fmaf(v2.w, w3, a2);
            a3 = fmaf(v3.x, w0, a3); a3 = fmaf(v3.y, w1, a3);
            a3 = fmaf(v3.z, w2, a3); a3 = fmaf(v3.w, w3, a3);
        }
        const int row = rowBase + r0;
        if (row + 0 < rowsTot)
            rec[(size_t)(row + 0) * REC_H + D_NODE + col] = __float2half(a0);
        if (row + 1 < rowsTot)
            rec[(size_t)(row + 1) * REC_H + D_NODE + col] = __float2half(a1);
        if (row + 2 < rowsTot)
            rec[(size_t)(row + 2) * REC_H + D_NODE + col] = __float2half(a2);
        if (row + 3 < rowsTot)
            rec[(size_t)(row + 3) * REC_H + D_NODE + col] = __float2half(a3);
    }
}

// ---------------------------------------------------------------------------
// Main edge pass: 8 lanes per edge, gathers 2 contiguous 384 B records.
//   cost = ||es-ea|| * sigmoid( dot(relu(P_s+P_a), W2) + b2 )
//   atomicAdd(segsum[s], exp(-cost/temp))   (no seg-max: vals in [-20,0])
// ---------------------------------------------------------------------------
__global__ void __launch_bounds__(256)
edge_main_kernel(const __half* __restrict__ recS,
                 const __half* __restrict__ recA,
                 const int* __restrict__ idx,
                 const float* __restrict__ W2,
                 const float* __restrict__ b2,
                 const float* __restrict__ logT,
                 float* __restrict__ out_costs,
                 float* __restrict__ segsum,
                 int E)
{
    const int gid = blockIdx.x * 256 + (int)threadIdx.x;
    const int e = gid >> 3;
    const int t = gid & 7;
    if (e >= E) return;

    const int s = idx[e];
    const int a = idx[E + e];

    const uint4* rs = (const uint4*)(recS + (size_t)s * REC_H);
    const uint4* ra = (const uint4*)(recA + (size_t)a * REC_H);

    // --- norm partial: e16 chunk t (8 halves) ---
    uint4 xs = rs[t];
    uint4 xa = ra[t];
    const __half2* hs = (const __half2*)&xs;
    const __half2* ha = (const __half2*)&xa;
    float nacc = 0.0f;
#pragma unroll
    for (int k = 0; k < 4; ++k) {
        float2 fs = __half22float2(hs[k]);
        float2 fa = __half22float2(ha[k]);
        float d0 = fs.x - fa.x, d1 = fs.y - fa.y;
        nacc = fmaf(d0, d0, nacc);
        nacc = fmaf(d1, d1, nacc);
    }

    // --- gate partials: P chunks t and t+8 (uint4 idx 8+t, 16+t) ---
    const float4* w4 = (const float4*)W2;
    float g = 0.0f;
#pragma unroll
    for (int c = 0; c < 2; ++c) {
        const int chunk = t + c * 8;
        uint4 up = rs[8 + chunk];
        uint4 uq = ra[8 + chunk];
        const __half2* hp = (const __half2*)&up;
        const __half2* hq = (const __half2*)&uq;
        float4 w0 = w4[chunk * 2];
        float4 w1 = w4[chunk * 2 + 1];
        float wv[8] = {w0.x, w0.y, w0.z, w0.w, w1.x, w1.y, w1.z, w1.w};
#pragma unroll
        for (int k = 0; k < 4; ++k) {
            float2 fp = __half22float2(hp[k]);
            float2 fq = __half22float2(hq[k]);
            float h0 = fmaxf(fp.x + fq.x, 0.0f);
            float h1 = fmaxf(fp.y + fq.y, 0.0f);
            g = fmaf(h0, wv[2 * k], g);
            g = fmaf(h1, wv[2 * k + 1], g);
        }
    }

    // --- 8-lane reduction ---
#pragma unroll
    for (int m = 1; m < 8; m <<= 1) {
        nacc += __shfl_xor(nacc, m);
        g    += __shfl_xor(g, m);
    }

    if (t == 0) {
        const float z = g + b2[0];
        const float gate = 1.0f / (1.0f + __expf(-z));
        const float cost = sqrtf(nacc) * gate;
        out_costs[e] = cost;
        const float temp = __expf(logT[0]);
        atomicAdd(&segsum[s], __expf(-cost / temp));
    }
}

// ---------------------------------------------------------------------------
// edge_weights = exp(-cost/temp) / segsum[s]  (recompute ex from cost)
// ---------------------------------------------------------------------------
__global__ void __launch_bounds__(256)
edge_norm_kernel(const int* __restrict__ idx,
                 const float* __restrict__ out_costs,
                 const float* __restrict__ segsum,
                 const float* __restrict__ logT,
                 float* __restrict__ out_w,
                 int E)
{
    const int e = blockIdx.x * blockDim.x + threadIdx.x;
    if (e >= E) return;
    const int s = idx[e];
    const float temp = __expf(logT[0]);
    const float ex = __expf(-out_costs[e] / temp);
    out_w[e] = ex / segsum[s];
}

// ---------------------------------------------------------------------------
extern "C" void kernel_launch(void* const* d_in, const int* in_sizes, int n_in,
                              void* d_out, int out_size, void* d_ws, size_t ws_size,
                              hipStream_t stream)
{
    const float* emb_s = (const float*)d_in[0];
    const float* emb_a = (const float*)d_in[1];
    const int*   idx   = (const int*)d_in[2];
    const float* W1    = (const float*)d_in[3];
    const float* b1    = (const float*)d_in[4];
    const float* W2    = (const float*)d_in[5];
    const float* b2    = (const float*)d_in[6];
    const float* logT  = (const float*)d_in[7];

    const int numS = in_sizes[0] / D_NODE;
    const int numA = in_sizes[1] / D_NODE;
    const int E    = in_sizes[2] / 2;

    float* out = (float*)d_out;            // [0,E) weights, [E,2E) costs

    // workspace layout (records are 384 B, 16 B aligned)
    char* ws = (char*)d_ws;
    __half* recS   = (__half*)ws;   ws += (size_t)numS * REC_H * sizeof(__half);
    __half* recA   = (__half*)ws;   ws += (size_t)numA * REC_H * sizeof(__half);
    float*  segsum = (float*)ws;

    // streaming prep: conversions into records + segsum zeroing (low VGPR)
    {
        const int total = numS * (D_NODE / 8) + numA * (D_NODE / 8) + numS;
        convert_zero_kernel<<<(total + 255) / 256, 256, 0, stream>>>(
            emb_s, emb_a, recS, recA, segsum, numS, numA);
    }

    // P precompute (LDS-staged, ILP-4)
    {
        const int pBlocks = (numS + 63) / 64 + (numA + 63) / 64;
        precompute_P_kernel<<<pBlocks, 256, 0, stream>>>(emb_s, emb_a, W1, b1,
                                                         recS, recA, numS, numA);
    }

    // main edge pass (8 lanes/edge)
    {
        const long long threads = (long long)E * 8;
        const int blocks = (int)((threads + 255) / 256);
        edge_main_kernel<<<blocks, 256, 0, stream>>>(recS, recA, idx, W2, b2,
                                                     logT, out + E, segsum, E);
    }

    edge_norm_kernel<<<(E + 255) / 256, 256, 0, stream>>>(idx, out + E, segsum,
                                                          logT, out, E);
}

// Round 6
// 142.048 us; speedup vs baseline: 1.5845x; 1.4182x over previous
//
#include <hip/hip_runtime.h>
#include <hip/hip_fp16.h>

#define D_NODE 64
#define H_DIM  128
#define REC_H  192   // halves per node record: 64 (e16) + 128 (P) = 384 B

struct Half8 { __half2 h[4]; };

#if defined(__has_builtin)
#  if __has_builtin(__builtin_amdgcn_fdot2)
#    define HAVE_FDOT2 1
#  endif
#endif

typedef _Float16 h2v __attribute__((ext_vector_type(2)));
struct H2x4 { h2v h[4]; };   // 16 B = 8 halves

// ---------------------------------------------------------------------------
// Fused prep kernel (uniform low-ish VGPR across roles):
//   blocks [0, pS+pA): per-block 64 node rows —
//     stage emb rows -> f16 (LDS + write e16 record region directly),
//     compute P = emb @ W1_half (+b1 for S) with w in half2 regs,
//     dot2 accumulation in f32, write P record region.
//   blocks [pS+pA, +zB): zero segsum.
// ---------------------------------------------------------------------------
__global__ void __launch_bounds__(256)
prep_kernel(const float* __restrict__ emb_s,
            const float* __restrict__ emb_a,
            const float* __restrict__ W1,
            const float* __restrict__ b1,
            __half* __restrict__ recS,
            __half* __restrict__ recA,
            float* __restrict__ segsum,
            int numS, int numA, int pS, int pA)
{
    const int tid = threadIdx.x;
    int b = blockIdx.x;

    if (b >= pS + pA) {                       // ---- role: zero segsum ----
        const int i = (b - pS - pA) * 256 + tid;
        if (i < numS) segsum[i] = 0.0f;
        return;
    }

    const bool isS = (b < pS);
    const int pb = isS ? b : b - pS;
    const float* etab = isS ? emb_s : emb_a;
    __half* rec = isS ? recS : recA;
    const int rowsTot = isS ? numS : numA;
    const int rowBase = pb * 64;

    __shared__ __half eT[64 * D_NODE];        // 8 KB (f16 rows)

    // ---- stage 64 rows: global f32 -> f16 -> LDS + e16 record write ----
    {
        const float4* src4 = (const float4*)(etab + (size_t)rowBase * D_NODE);
#pragma unroll
        for (int it = 0; it < 2; ++it) {
            const int c = tid + it * 256;     // chunk of 8 halves; 512 total
            const int row = c >> 3;           // 0..63
            const int sub = c & 7;
            const bool ok = (rowBase + row < rowsTot);
            float4 a = make_float4(0.f, 0.f, 0.f, 0.f), d = a;
            if (ok) { a = src4[2 * c]; d = src4[2 * c + 1]; }
            Half8 o;
            o.h[0] = __floats2half2_rn(a.x, a.y);
            o.h[1] = __floats2half2_rn(a.z, a.w);
            o.h[2] = __floats2half2_rn(d.x, d.y);
            o.h[3] = __floats2half2_rn(d.z, d.w);
            ((Half8*)eT)[c] = o;
            if (ok)
                ((Half8*)(rec + (size_t)(rowBase + row) * REC_H))[sub] = o;
        }
    }

    // ---- W column (f16 pairs) in registers ----
    const int col = tid & 127;
    const int rhalf = tid >> 7;               // 0/1: which 32-row half
    const float* Wh = isS ? W1 : (W1 + D_NODE * H_DIM);
    h2v w2[32];
#pragma unroll
    for (int k = 0; k < 32; ++k) {
        w2[k][0] = (_Float16)Wh[(2 * k) * H_DIM + col];
        w2[k][1] = (_Float16)Wh[(2 * k + 1) * H_DIM + col];
    }
    const float bias = isS ? b1[col] : 0.0f;

    __syncthreads();

    // ---- ILP-4 over 32 rows; b128 LDS reads (8 halves), dot2 into f32 ----
    for (int r0 = rhalf * 32; r0 < rhalf * 32 + 32; r0 += 4) {
        const H2x4* e0 = (const H2x4*)&eT[(r0 + 0) * D_NODE];
        const H2x4* e1 = (const H2x4*)&eT[(r0 + 1) * D_NODE];
        const H2x4* e2 = (const H2x4*)&eT[(r0 + 2) * D_NODE];
        const H2x4* e3 = (const H2x4*)&eT[(r0 + 3) * D_NODE];
        float a0 = bias, a1 = bias, a2 = bias, a3 = bias;
#pragma unroll
        for (int k8 = 0; k8 < D_NODE / 8; ++k8) {      // 8 iters
            const H2x4 v0 = e0[k8];
            const H2x4 v1 = e1[k8];
            const H2x4 v2 = e2[k8];
            const H2x4 v3 = e3[k8];
#pragma unroll
            for (int j = 0; j < 4; ++j) {
                const h2v w = w2[4 * k8 + j];
#ifdef HAVE_FDOT2
                a0 = __builtin_amdgcn_fdot2(v0.h[j], w, a0, false);
                a1 = __builtin_amdgcn_fdot2(v1.h[j], w, a1, false);
                a2 = __builtin_amdgcn_fdot2(v2.h[j], w, a2, false);
                a3 = __builtin_amdgcn_fdot2(v3.h[j], w, a3, false);
#else
                const float wx = (float)w[0], wy = (float)w[1];
                a0 = fmaf((float)v0.h[j][0], wx, a0); a0 = fmaf((float)v0.h[j][1], wy, a0);
                a1 = fmaf((float)v1.h[j][0], wx, a1); a1 = fmaf((float)v1.h[j][1], wy, a1);
                a2 = fmaf((float)v2.h[j][0], wx, a2); a2 = fmaf((float)v2.h[j][1], wy, a2);
                a3 = fmaf((float)v3.h[j][0], wx, a3); a3 = fmaf((float)v3.h[j][1], wy, a3);
#endif
            }
        }
        const int row = rowBase + r0;
        if (row + 0 < rowsTot)
            rec[(size_t)(row + 0) * REC_H + D_NODE + col] = __float2half(a0);
        if (row + 1 < rowsTot)
            rec[(size_t)(row + 1) * REC_H + D_NODE + col] = __float2half(a1);
        if (row + 2 < rowsTot)
            rec[(size_t)(row + 2) * REC_H + D_NODE + col] = __float2half(a2);
        if (row + 3 < rowsTot)
            rec[(size_t)(row + 3) * REC_H + D_NODE + col] = __float2half(a3);
    }
}

// ---------------------------------------------------------------------------
// Main edge pass: 8 lanes per edge, gathers 2 contiguous 384 B records.
//   cost = ||es-ea|| * sigmoid( dot(relu(P_s+P_a), W2) + b2 )
//   atomicAdd(segsum[s], exp(-cost/temp))   (no seg-max: vals in [-20,0])
// ---------------------------------------------------------------------------
__global__ void __launch_bounds__(256)
edge_main_kernel(const __half* __restrict__ recS,
                 const __half* __restrict__ recA,
                 const int* __restrict__ idx,
                 const float* __restrict__ W2,
                 const float* __restrict__ b2,
                 const float* __restrict__ logT,
                 float* __restrict__ out_costs,
                 float* __restrict__ segsum,
                 int E)
{
    const int gid = blockIdx.x * 256 + (int)threadIdx.x;
    const int e = gid >> 3;
    const int t = gid & 7;
    if (e >= E) return;

    const int s = idx[e];
    const int a = idx[E + e];

    const uint4* rs = (const uint4*)(recS + (size_t)s * REC_H);
    const uint4* ra = (const uint4*)(recA + (size_t)a * REC_H);

    // --- norm partial: e16 chunk t (8 halves) ---
    uint4 xs = rs[t];
    uint4 xa = ra[t];
    const __half2* hs = (const __half2*)&xs;
    const __half2* ha = (const __half2*)&xa;
    float nacc = 0.0f;
#pragma unroll
    for (int k = 0; k < 4; ++k) {
        float2 fs = __half22float2(hs[k]);
        float2 fa = __half22float2(ha[k]);
        float d0 = fs.x - fa.x, d1 = fs.y - fa.y;
        nacc = fmaf(d0, d0, nacc);
        nacc = fmaf(d1, d1, nacc);
    }

    // --- gate partials: P chunks t and t+8 (uint4 idx 8+t, 16+t) ---
    const float4* w4 = (const float4*)W2;
    float g = 0.0f;
#pragma unroll
    for (int c = 0; c < 2; ++c) {
        const int chunk = t + c * 8;
        uint4 up = rs[8 + chunk];
        uint4 uq = ra[8 + chunk];
        const __half2* hp = (const __half2*)&up;
        const __half2* hq = (const __half2*)&uq;
        float4 w0 = w4[chunk * 2];
        float4 w1 = w4[chunk * 2 + 1];
        float wv[8] = {w0.x, w0.y, w0.z, w0.w, w1.x, w1.y, w1.z, w1.w};
#pragma unroll
        for (int k = 0; k < 4; ++k) {
            float2 fp = __half22float2(hp[k]);
            float2 fq = __half22float2(hq[k]);
            float h0 = fmaxf(fp.x + fq.x, 0.0f);
            float h1 = fmaxf(fp.y + fq.y, 0.0f);
            g = fmaf(h0, wv[2 * k], g);
            g = fmaf(h1, wv[2 * k + 1], g);
        }
    }

    // --- 8-lane reduction ---
#pragma unroll
    for (int m = 1; m < 8; m <<= 1) {
        nacc += __shfl_xor(nacc, m);
        g    += __shfl_xor(g, m);
    }

    if (t == 0) {
        const float z = g + b2[0];
        const float gate = 1.0f / (1.0f + __expf(-z));
        const float cost = sqrtf(nacc) * gate;
        out_costs[e] = cost;
        const float temp = __expf(logT[0]);
        atomicAdd(&segsum[s], __expf(-cost / temp));
    }
}

// ---------------------------------------------------------------------------
// edge_weights = exp(-cost/temp) / segsum[s]  (recompute ex from cost)
// ---------------------------------------------------------------------------
__global__ void __launch_bounds__(256)
edge_norm_kernel(const int* __restrict__ idx,
                 const float* __restrict__ out_costs,
                 const float* __restrict__ segsum,
                 const float* __restrict__ logT,
                 float* __restrict__ out_w,
                 int E)
{
    const int e = blockIdx.x * blockDim.x + threadIdx.x;
    if (e >= E) return;
    const int s = idx[e];
    const float temp = __expf(logT[0]);
    const float ex = __expf(-out_costs[e] / temp);
    out_w[e] = ex / segsum[s];
}

// ---------------------------------------------------------------------------
extern "C" void kernel_launch(void* const* d_in, const int* in_sizes, int n_in,
                              void* d_out, int out_size, void* d_ws, size_t ws_size,
                              hipStream_t stream)
{
    const float* emb_s = (const float*)d_in[0];
    const float* emb_a = (const float*)d_in[1];
    const int*   idx   = (const int*)d_in[2];
    const float* W1    = (const float*)d_in[3];
    const float* b1    = (const float*)d_in[4];
    const float* W2    = (const float*)d_in[5];
    const float* b2    = (const float*)d_in[6];
    const float* logT  = (const float*)d_in[7];

    const int numS = in_sizes[0] / D_NODE;
    const int numA = in_sizes[1] / D_NODE;
    const int E    = in_sizes[2] / 2;

    float* out = (float*)d_out;            // [0,E) weights, [E,2E) costs

    // workspace layout (records are 384 B, 16 B aligned)
    char* ws = (char*)d_ws;
    __half* recS   = (__half*)ws;   ws += (size_t)numS * REC_H * sizeof(__half);
    __half* recA   = (__half*)ws;   ws += (size_t)numA * REC_H * sizeof(__half);
    float*  segsum = (float*)ws;

    // fused prep: convert+P+zero in one launch
    const int pS = (numS + 63) / 64;
    const int pA = (numA + 63) / 64;
    const int zB = (numS + 255) / 256;
    prep_kernel<<<pS + pA + zB, 256, 0, stream>>>(emb_s, emb_a, W1, b1,
                                                  recS, recA, segsum,
                                                  numS, numA, pS, pA);

    // main edge pass (8 lanes/edge)
    {
        const long long threads = (long long)E * 8;
        const int blocks = (int)((threads + 255) / 256);
        edge_main_kernel<<<blocks, 256, 0, stream>>>(recS, recA, idx, W2, b2,
                                                     logT, out + E, segsum, E);
    }

    edge_norm_kernel<<<(E + 255) / 256, 256, 0, stream>>>(idx, out + E, segsum,
                                                          logT, out, E);
}